// Round 1
// baseline (564.435 us; speedup 1.0000x reference)
//
#include <hip/hip_runtime.h>
#include <stdint.h>

typedef float f32x4 __attribute__((ext_vector_type(4)));
typedef short bf16x8 __attribute__((ext_vector_type(8)));

#define IN_DIM   25088
#define OUT_DIM  4096
#define BATCH    64
#define SPLITS   28
#define KBLK     64
#define NBLK     14        // KBLK*NBLK = 896 = IN_DIM/SPLITS exactly
#define WG_N     128
#define LSTR     72        // LDS row stride in bf16 elems (64 + 8 pad = 144B, 16B-aligned)

// fp32 -> bf16 bits, round-to-nearest-even
__device__ __forceinline__ uint32_t f2bf(float f) {
    uint32_t u = __builtin_bit_cast(uint32_t, f);
    return (u + 0x7FFFu + ((u >> 16) & 1u)) >> 16;
}

// out[b][o] = bias[o]  (out is re-poisoned before every replay)
__global__ void init_out(const float* __restrict__ bias, float* __restrict__ out) {
    int idx = blockIdx.x * 256 + threadIdx.x;
    out[idx] = bias[idx & (OUT_DIM - 1)];
}

__global__ __launch_bounds__(256) void qlinear_main(
    const float* __restrict__ x,        // [64, 25088] fp32
    const int*   __restrict__ labels,   // [4096, 25088] int32 in [0,32)
    const float* __restrict__ centroids,// [32] fp32
    float* __restrict__ out)            // [64, 4096] fp32, pre-init with bias
{
    __shared__ __align__(16) uint32_t table[1024];          // pair dequant table
    __shared__ __align__(16) uint16_t wt[WG_N * LSTR];      // dequant W tile [128][72] bf16
    __shared__ __align__(16) uint16_t xt[BATCH * LSTR];     // x tile [64][72] bf16

    const int t = threadIdx.x;
    const int ntiles = OUT_DIM / WG_N;            // 32
    const int wgn   = blockIdx.x % ntiles;
    const int split = blockIdx.x / ntiles;        // 0..27
    const int o0    = wgn * WG_N;
    const int kbase = split * (KBLK * NBLK);

    // Build pair table: entry i = bf16(c[i&31]) | bf16(c[i>>5])<<16
    // (low half = earlier-k element, matching little-endian LDS layout)
    #pragma unroll
    for (int e = 0; e < 4; ++e) {
        int i = t + 256 * e;
        table[i] = f2bf(centroids[i & 31]) | (f2bf(centroids[i >> 5]) << 16);
    }

    f32x4 acc[4][2] = {};   // [m-tile 0..3 = batch 16s][n-tile 0..1 = out 16s]

    const int lane = t & 63;
    const int wave = t >> 6;       // 0..3 -> 32 out-rows each
    const int ln   = lane & 15;
    const int lq   = lane >> 4;    // 0..3

    for (int blk = 0; blk < NBLK; ++blk) {
        const int k0 = kbase + blk * KBLK;
        __syncthreads();   // LDS safe to overwrite (also covers table build on blk==0)

        // ---- stage W tile: 128 rows x 64 k, dequantized via pair table ----
        {
            const int rp  = t >> 4;          // 0..15
            const int kq4 = (t & 15) * 4;    // element offset, 4 labels per thread
            #pragma unroll
            for (int pass = 0; pass < 8; ++pass) {
                const int row = pass * 16 + rp;
                const int4 lv = *(const int4*)(labels + (size_t)(o0 + row) * IN_DIM + k0 + kq4);
                const uint32_t v01 = table[(uint32_t)lv.x | ((uint32_t)lv.y << 5)];
                const uint32_t v23 = table[(uint32_t)lv.z | ((uint32_t)lv.w << 5)];
                *(uint2*)(wt + row * LSTR + kq4) = make_uint2(v01, v23);
            }
        }
        // ---- stage x tile: 64 rows x 64 k, fp32 -> bf16 inline ----
        {
            const int row = t >> 2;          // 0..63
            const int seg = (t & 3) * 16;    // 16 floats per thread
            const float* xp = x + (size_t)row * IN_DIM + k0 + seg;
            uint16_t* xw = xt + row * LSTR + seg;
            #pragma unroll
            for (int j = 0; j < 4; ++j) {
                const float4 v = *(const float4*)(xp + j * 4);
                const uint32_t p0 = f2bf(v.x) | (f2bf(v.y) << 16);
                const uint32_t p1 = f2bf(v.z) | (f2bf(v.w) << 16);
                *(uint2*)(xw + j * 4) = make_uint2(p0, p1);
            }
        }
        __syncthreads();

        // ---- consume: 2 k-steps of 32, MFMA 16x16x32 bf16 ----
        #pragma unroll
        for (int ks = 0; ks < 2; ++ks) {
            const int kk = ks * 32 + lq * 8;   // A/B frag: elem=lane&15 row, k=(lane>>4)*8+j
            bf16x8 a[4], b[2];
            #pragma unroll
            for (int mt = 0; mt < 4; ++mt)
                a[mt] = *(const bf16x8*)(xt + (mt * 16 + ln) * LSTR + kk);
            #pragma unroll
            for (int nt = 0; nt < 2; ++nt)
                b[nt] = *(const bf16x8*)(wt + (wave * 32 + nt * 16 + ln) * LSTR + kk);
            #pragma unroll
            for (int mt = 0; mt < 4; ++mt)
                #pragma unroll
                for (int nt = 0; nt < 2; ++nt)
                    acc[mt][nt] = __builtin_amdgcn_mfma_f32_16x16x32_bf16(
                        a[mt], b[nt], acc[mt][nt], 0, 0, 0);
        }
    }

    // ---- epilogue: C/D layout col=lane&15 (out dim), row=(lane>>4)*4+reg (batch dim) ----
    #pragma unroll
    for (int mt = 0; mt < 4; ++mt) {
        #pragma unroll
        for (int nt = 0; nt < 2; ++nt) {
            const int o = o0 + wave * 32 + nt * 16 + ln;
            #pragma unroll
            for (int r = 0; r < 4; ++r) {
                const int brow = mt * 16 + lq * 4 + r;
                atomicAdd(out + (size_t)brow * OUT_DIM + o, acc[mt][nt][r]);
            }
        }
    }
}

extern "C" void kernel_launch(void* const* d_in, const int* in_sizes, int n_in,
                              void* d_out, int out_size, void* d_ws, size_t ws_size,
                              hipStream_t stream) {
    const float* x         = (const float*)d_in[0];
    const int*   labels    = (const int*)d_in[1];
    const float* centroids = (const float*)d_in[2];
    const float* bias      = (const float*)d_in[3];
    float* out = (float*)d_out;

    init_out<<<(BATCH * OUT_DIM) / 256, 256, 0, stream>>>(bias, out);
    qlinear_main<<<(OUT_DIM / WG_N) * SPLITS, 256, 0, stream>>>(x, labels, centroids, out);
}

// Round 2
// 563.604 us; speedup vs baseline: 1.0015x; 1.0015x over previous
//
#include <hip/hip_runtime.h>
#include <stdint.h>

typedef float f32x4 __attribute__((ext_vector_type(4)));
typedef short bf16x8 __attribute__((ext_vector_type(8)));

#define IN_DIM   25088
#define OUT_DIM  4096
#define BATCH    64
#define SPLITS   28
#define KBLK     64
#define NBLK     14        // KBLK*NBLK = 896 = IN_DIM/SPLITS exactly
#define WG_N     128
#define LSTR     72        // LDS W-row stride in bf16 elems (64 + 8 pad, 16B-aligned)

// fp32 -> bf16 bits, round-to-nearest-even
__device__ __forceinline__ uint32_t f2bf(float f) {
    uint32_t u = __builtin_bit_cast(uint32_t, f);
    return (u + 0x7FFFu + ((u >> 16) & 1u)) >> 16;
}
__device__ __forceinline__ uint32_t pack2(float a, float b) {
    return f2bf(a) | (f2bf(b) << 16);
}

// ---- kernel 1: x fp32 [64,25088] -> bf16 (as packed u32) into d_ws ----
__global__ __launch_bounds__(256) void convert_x(const float* __restrict__ x,
                                                 uint32_t* __restrict__ xb) {
    const size_t i = blockIdx.x * 256 + threadIdx.x;  // 8 floats -> 4 u32 per thread
    const float4 v0 = *(const float4*)(x + i * 8);
    const float4 v1 = *(const float4*)(x + i * 8 + 4);
    uint4 o;
    o.x = pack2(v0.x, v0.y); o.y = pack2(v0.z, v0.w);
    o.z = pack2(v1.x, v1.y); o.w = pack2(v1.z, v1.w);
    *(uint4*)(xb + i * 4) = o;
}

// ---- kernel 2: main GEMM, per-split partials (no atomics) ----
__global__ __launch_bounds__(256) void qlinear_main(
    const int*      __restrict__ labels,    // [4096, 25088] int32 in [0,32)
    const float*    __restrict__ centroids, // [32]
    const uint16_t* __restrict__ xb,        // [64, 25088] bf16 (precomputed)
    float*          __restrict__ part)      // [SPLITS, 64, 4096] fp32
{
    __shared__ __align__(16) uint32_t table[1024];       // pair dequant table
    __shared__ __align__(16) uint16_t wt[WG_N * LSTR];   // W tile [128][72] bf16

    const int t     = threadIdx.x;
    const int wgn   = blockIdx.x & 31;      // OUT_DIM / WG_N = 32 tiles
    const int split = blockIdx.x >> 5;      // 0..27
    const int o0    = wgn * WG_N;
    const int kbase = split * (KBLK * NBLK);

    // pair table: entry i = bf16(c[i&31]) | bf16(c[i>>5])<<16 (low = earlier k)
    #pragma unroll
    for (int e = 0; e < 4; ++e) {
        const int i = t + 256 * e;
        table[i] = f2bf(centroids[i & 31]) | (f2bf(centroids[i >> 5]) << 16);
    }

    const int lane = t & 63;
    const int wave = t >> 6;      // 0..3 -> 32 out-rows each
    const int ln   = lane & 15;
    const int lq   = lane >> 4;   // 0..3

    const int srow = t >> 3;        // staging: 32 rows per pass
    const int skc  = (t & 7) * 8;   // 8 consecutive k per thread

    f32x4 acc[4][2] = {};   // [batch 16s][out 16s]

    for (int blk = 0; blk < NBLK; ++blk) {
        const int k0 = kbase + blk * KBLK;

        // A-frag prefetch straight from global bf16 x (independent of LDS/barrier).
        // A[m][k]: m = lane&15 (row), k = (lane>>4)*8 + j
        bf16x8 a[2][4];
        #pragma unroll
        for (int ks = 0; ks < 2; ++ks)
            #pragma unroll
            for (int mt = 0; mt < 4; ++mt)
                a[ks][mt] = *(const bf16x8*)(xb + (size_t)(mt * 16 + ln) * IN_DIM
                                             + k0 + ks * 32 + lq * 8);

        __syncthreads();   // wt safe to overwrite (covers table build on blk==0)

        // stage W tile: 128 rows x 64 k, dequant via pair table, b128 LDS writes
        #pragma unroll
        for (int p = 0; p < 4; ++p) {
            const int row = p * 32 + srow;
            const int* lp = labels + (size_t)(o0 + row) * IN_DIM + k0 + skc;
            const int4 l0 = *(const int4*)lp;
            const int4 l1 = *(const int4*)(lp + 4);
            uint4 w;
            w.x = table[(uint32_t)l0.x | ((uint32_t)l0.y << 5)];
            w.y = table[(uint32_t)l0.z | ((uint32_t)l0.w << 5)];
            w.z = table[(uint32_t)l1.x | ((uint32_t)l1.y << 5)];
            w.w = table[(uint32_t)l1.z | ((uint32_t)l1.w << 5)];
            *(uint4*)(wt + row * LSTR + skc) = w;
        }
        __syncthreads();

        #pragma unroll
        for (int ks = 0; ks < 2; ++ks) {
            const int kk = ks * 32 + lq * 8;
            bf16x8 b[2];
            #pragma unroll
            for (int nt = 0; nt < 2; ++nt)
                b[nt] = *(const bf16x8*)(wt + (wave * 32 + nt * 16 + ln) * LSTR + kk);
            #pragma unroll
            for (int mt = 0; mt < 4; ++mt)
                #pragma unroll
                for (int nt = 0; nt < 2; ++nt)
                    acc[mt][nt] = __builtin_amdgcn_mfma_f32_16x16x32_bf16(
                        a[ks][mt], b[nt], acc[mt][nt], 0, 0, 0);
        }
    }

    // epilogue: C/D layout col=lane&15 (out), row=(lane>>4)*4+reg (batch); plain stores
    float* pout = part + (size_t)split * (BATCH * OUT_DIM);
    #pragma unroll
    for (int mt = 0; mt < 4; ++mt)
        #pragma unroll
        for (int nt = 0; nt < 2; ++nt) {
            const int o = o0 + wave * 32 + nt * 16 + ln;
            #pragma unroll
            for (int r = 0; r < 4; ++r)
                pout[(size_t)(mt * 16 + lq * 4 + r) * OUT_DIM + o] = acc[mt][nt][r];
        }
}

// ---- kernel 3: out = bias + sum over splits ----
__global__ __launch_bounds__(256) void reduce_out(const float* __restrict__ part,
                                                  const float* __restrict__ bias,
                                                  float* __restrict__ out) {
    const size_t i = blockIdx.x * 256 + threadIdx.x;   // float4 index
    float4 s = *(const float4*)(bias + ((i * 4) & (OUT_DIM - 1)));
    #pragma unroll
    for (int sp = 0; sp < SPLITS; ++sp) {
        const float4 p = *(const float4*)(part + (size_t)sp * (BATCH * OUT_DIM) + i * 4);
        s.x += p.x; s.y += p.y; s.z += p.z; s.w += p.w;
    }
    *(float4*)(out + i * 4) = s;
}

extern "C" void kernel_launch(void* const* d_in, const int* in_sizes, int n_in,
                              void* d_out, int out_size, void* d_ws, size_t ws_size,
                              hipStream_t stream) {
    const float* x         = (const float*)d_in[0];
    const int*   labels    = (const int*)d_in[1];
    const float* centroids = (const float*)d_in[2];
    const float* bias      = (const float*)d_in[3];
    float* out = (float*)d_out;

    uint32_t* xb   = (uint32_t*)d_ws;                                  // 3.2 MB bf16 x
    float*    part = (float*)((char*)d_ws + (size_t)BATCH * IN_DIM * 2); // 28 MB partials

    convert_x<<<(BATCH * IN_DIM) / 2048, 256, 0, stream>>>(x, xb);
    qlinear_main<<<32 * SPLITS, 256, 0, stream>>>(labels, centroids,
                                                  (const uint16_t*)xb, part);
    reduce_out<<<(BATCH * OUT_DIM) / 1024, 256, 0, stream>>>(part, bias, out);
}

// Round 3
// 550.902 us; speedup vs baseline: 1.0246x; 1.0231x over previous
//
#include <hip/hip_runtime.h>
#include <stdint.h>

typedef float f32x4 __attribute__((ext_vector_type(4)));
typedef short bf16x8 __attribute__((ext_vector_type(8)));
typedef int   i32x4  __attribute__((ext_vector_type(4)));
typedef unsigned int u32x4 __attribute__((ext_vector_type(4)));

#define IN_DIM   25088
#define OUT_DIM  4096
#define BATCH    64
#define SPLITS   28
#define KBLK     64
#define NBLK     14        // KBLK*NBLK = 896 = IN_DIM/SPLITS exactly
#define WG_N     128
#define LSTR     72        // LDS row stride in bf16 elems (64 + 8 pad, 16B-aligned)

// fp32 -> bf16 bits, round-to-nearest-even
__device__ __forceinline__ uint32_t f2bf(float f) {
    uint32_t u = __builtin_bit_cast(uint32_t, f);
    return (u + 0x7FFFu + ((u >> 16) & 1u)) >> 16;
}
__device__ __forceinline__ uint32_t pack2(float a, float b) {
    return f2bf(a) | (f2bf(b) << 16);
}

// ---- kernel 1: x fp32 [64,25088] -> bf16 (as packed u32) into d_ws ----
__global__ __launch_bounds__(256) void convert_x(const float* __restrict__ x,
                                                 uint32_t* __restrict__ xb) {
    const size_t i = blockIdx.x * 256 + threadIdx.x;  // 8 floats -> 4 u32 per thread
    const float4 v0 = *(const float4*)(x + i * 8);
    const float4 v1 = *(const float4*)(x + i * 8 + 4);
    uint4 o;
    o.x = pack2(v0.x, v0.y); o.y = pack2(v0.z, v0.w);
    o.z = pack2(v1.x, v1.y); o.w = pack2(v1.z, v1.w);
    *(uint4*)(xb + i * 4) = o;
}

// ---- kernel 2: main GEMM, per-split partials (no atomics) ----
__global__ __launch_bounds__(256) void qlinear_main(
    const int*      __restrict__ labels,    // [4096, 25088] int32 in [0,32)
    const float*    __restrict__ centroids, // [32]
    const uint16_t* __restrict__ xb,        // [64, 25088] bf16 (precomputed)
    float*          __restrict__ part)      // [SPLITS, 64, 4096] fp32
{
    __shared__ __align__(16) uint32_t table[1024];       // pair dequant table
    __shared__ __align__(16) uint16_t wt[WG_N * LSTR];   // W tile [128][72] bf16
    __shared__ __align__(16) uint16_t xt[BATCH * LSTR];  // x tile [64][72] bf16

    const int t     = threadIdx.x;
    const int wgn   = blockIdx.x & 31;      // OUT_DIM / WG_N = 32 tiles
    const int split = blockIdx.x >> 5;      // 0..27
    const int o0    = wgn * WG_N;
    const int kbase = split * (KBLK * NBLK);

    // pair table: entry i = bf16(c[i&31]) | bf16(c[i>>5])<<16 (low = earlier k)
    #pragma unroll
    for (int e = 0; e < 4; ++e) {
        const int i = t + 256 * e;
        table[i] = f2bf(centroids[i & 31]) | (f2bf(centroids[i >> 5]) << 16);
    }

    const int lane = t & 63;
    const int wave = t >> 6;      // 0..3 -> 32 out-rows each
    const int ln   = lane & 15;
    const int lq   = lane >> 4;   // 0..3

    const int srow = t >> 3;        // W staging: 32 rows per pass
    const int skc  = (t & 7) * 8;   // 8 consecutive k per thread

    const int xrow = t >> 2;        // x staging: 64 rows, 4 threads/row
    const int xseg = (t & 3) * 16;  // 16 bf16 elems per thread

    f32x4 acc[4][2] = {};   // [batch 16s][out 16s]

    for (int blk = 0; blk < NBLK; ++blk) {
        const int k0 = kbase + blk * KBLK;

        __syncthreads();   // wt/xt safe to overwrite (covers table build on blk==0)

        // ---- stage W tile: 128 rows x 64 k, dequant via pair table ----
        // labels are a read-once 411 MB stream: nontemporal so they don't
        // evict the L2-resident xb (3.2 MB) and partials don't re-fetch.
        #pragma unroll
        for (int p = 0; p < 4; ++p) {
            const int row = p * 32 + srow;
            const i32x4* lp = (const i32x4*)(labels + (size_t)(o0 + row) * IN_DIM + k0 + skc);
            const i32x4 l0 = __builtin_nontemporal_load(lp);
            const i32x4 l1 = __builtin_nontemporal_load(lp + 1);
            uint4 w;
            w.x = table[(uint32_t)l0.x | ((uint32_t)l0.y << 5)];
            w.y = table[(uint32_t)l0.z | ((uint32_t)l0.w << 5)];
            w.z = table[(uint32_t)l1.x | ((uint32_t)l1.y << 5)];
            w.w = table[(uint32_t)l1.z | ((uint32_t)l1.w << 5)];
            *(uint4*)(wt + row * LSTR + skc) = w;
        }
        // ---- stage x tile: 64 rows x 64 k bf16 copy (temporal: reused by all WGs) ----
        {
            const uint16_t* xp = xb + (size_t)xrow * IN_DIM + k0 + xseg;
            const bf16x8 v0 = *(const bf16x8*)xp;
            const bf16x8 v1 = *(const bf16x8*)(xp + 8);
            *(bf16x8*)(xt + xrow * LSTR + xseg)     = v0;
            *(bf16x8*)(xt + xrow * LSTR + xseg + 8) = v1;
        }
        __syncthreads();

        // ---- consume: 2 k-steps of 32, MFMA 16x16x32 bf16 ----
        #pragma unroll
        for (int ks = 0; ks < 2; ++ks) {
            const int kk = ks * 32 + lq * 8;   // frag: m/n = lane&15, k = (lane>>4)*8 + j
            bf16x8 a[4], b[2];
            #pragma unroll
            for (int mt = 0; mt < 4; ++mt)
                a[mt] = *(const bf16x8*)(xt + (mt * 16 + ln) * LSTR + kk);
            #pragma unroll
            for (int nt = 0; nt < 2; ++nt)
                b[nt] = *(const bf16x8*)(wt + (wave * 32 + nt * 16 + ln) * LSTR + kk);
            #pragma unroll
            for (int mt = 0; mt < 4; ++mt)
                #pragma unroll
                for (int nt = 0; nt < 2; ++nt)
                    acc[mt][nt] = __builtin_amdgcn_mfma_f32_16x16x32_bf16(
                        a[mt], b[nt], acc[mt][nt], 0, 0, 0);
        }
    }

    // epilogue: C/D layout col=lane&15 (out), row=(lane>>4)*4+reg (batch).
    // Partials are write-once: nontemporal stores keep them out of L2.
    float* pout = part + (size_t)split * (BATCH * OUT_DIM);
    #pragma unroll
    for (int mt = 0; mt < 4; ++mt)
        #pragma unroll
        for (int nt = 0; nt < 2; ++nt) {
            const int o = o0 + wave * 32 + nt * 16 + ln;
            #pragma unroll
            for (int r = 0; r < 4; ++r)
                __builtin_nontemporal_store(
                    acc[mt][nt][r],
                    pout + (size_t)(mt * 16 + lq * 4 + r) * OUT_DIM + o);
        }
}

// ---- kernel 3: out = bias + sum over splits ----
__global__ __launch_bounds__(256) void reduce_out(const float* __restrict__ part,
                                                  const float* __restrict__ bias,
                                                  float* __restrict__ out) {
    const size_t i = blockIdx.x * 256 + threadIdx.x;   // float4 index
    float4 s = *(const float4*)(bias + ((i * 4) & (OUT_DIM - 1)));
    #pragma unroll
    for (int sp = 0; sp < SPLITS; ++sp) {
        const f32x4 p = __builtin_nontemporal_load(
            (const f32x4*)(part + (size_t)sp * (BATCH * OUT_DIM) + i * 4));
        s.x += p.x; s.y += p.y; s.z += p.z; s.w += p.w;
    }
    *(float4*)(out + i * 4) = s;
}

extern "C" void kernel_launch(void* const* d_in, const int* in_sizes, int n_in,
                              void* d_out, int out_size, void* d_ws, size_t ws_size,
                              hipStream_t stream) {
    const float* x         = (const float*)d_in[0];
    const int*   labels    = (const int*)d_in[1];
    const float* centroids = (const float*)d_in[2];
    const float* bias      = (const float*)d_in[3];
    float* out = (float*)d_out;

    uint32_t* xb   = (uint32_t*)d_ws;                                    // 3.2 MB bf16 x
    float*    part = (float*)((char*)d_ws + (size_t)BATCH * IN_DIM * 2); // 28 MB partials

    convert_x<<<(BATCH * IN_DIM) / 2048, 256, 0, stream>>>(x, xb);
    qlinear_main<<<32 * SPLITS, 256, 0, stream>>>(labels, centroids,
                                                  (const uint16_t*)xb, part);
    reduce_out<<<(BATCH * OUT_DIM) / 1024, 256, 0, stream>>>(part, bias, out);
}

// Round 4
// 545.455 us; speedup vs baseline: 1.0348x; 1.0100x over previous
//
#include <hip/hip_runtime.h>
#include <stdint.h>

typedef float f32x4 __attribute__((ext_vector_type(4)));
typedef short bf16x8 __attribute__((ext_vector_type(8)));
typedef int   i32x4  __attribute__((ext_vector_type(4)));

#define IN_DIM   25088
#define OUT_DIM  4096
#define BATCH    64
#define SPLITS   28
#define KBLK     64
#define NBLK     14        // KBLK*NBLK = 896 = IN_DIM/SPLITS exactly
#define WG_N     128
#define LSTR     72        // LDS row stride in bf16 elems (64 + 8 pad, 16B-aligned)

#define CONV_BLOCKS 784    // convert_x part: 784*256*8 = 64*25088 floats
#define INIT_BLOCKS 64     // out-init part: 64*256*16 = 64*4096 floats

// fp32 -> bf16 bits, round-to-nearest-even
__device__ __forceinline__ uint32_t f2bf(float f) {
    uint32_t u = __builtin_bit_cast(uint32_t, f);
    return (u + 0x7FFFu + ((u >> 16) & 1u)) >> 16;
}
__device__ __forceinline__ uint32_t pack2(float a, float b) {
    return f2bf(a) | (f2bf(b) << 16);
}

// ---- kernel 1 (fused prep): x fp32 -> bf16 into d_ws, AND out = bias ----
__global__ __launch_bounds__(256) void prep(const float* __restrict__ x,
                                            const float* __restrict__ bias,
                                            uint32_t* __restrict__ xb,
                                            float* __restrict__ out) {
    if (blockIdx.x < CONV_BLOCKS) {
        const size_t i = blockIdx.x * 256 + threadIdx.x;  // 8 floats -> 4 u32
        const float4 v0 = *(const float4*)(x + i * 8);
        const float4 v1 = *(const float4*)(x + i * 8 + 4);
        uint4 o;
        o.x = pack2(v0.x, v0.y); o.y = pack2(v0.z, v0.w);
        o.z = pack2(v1.x, v1.y); o.w = pack2(v1.z, v1.w);
        *(uint4*)(xb + i * 4) = o;
    } else {
        // out[b][o] = bias[o]; 16384 threads x 4 float4 = 64*4096 floats
        const size_t g = (size_t)(blockIdx.x - CONV_BLOCKS) * 256 + threadIdx.x;
        const float4* b4 = (const float4*)bias;
        float4* o4 = (float4*)out;
        #pragma unroll
        for (int r = 0; r < 4; ++r) {
            const size_t j = g * 4 + r;
            o4[j] = b4[j & (OUT_DIM / 4 - 1)];
        }
    }
}

// ---- kernel 2: main GEMM, atomic epilogue onto bias-initialized out ----
__global__ __launch_bounds__(256) void qlinear_main(
    const int*      __restrict__ labels,    // [4096, 25088] int32 in [0,32)
    const float*    __restrict__ centroids, // [32]
    const uint16_t* __restrict__ xb,        // [64, 25088] bf16 (precomputed)
    float*          __restrict__ out)       // [64, 4096] fp32, pre-init = bias
{
    __shared__ __align__(16) uint32_t table[1024];       // pair dequant table
    __shared__ __align__(16) uint16_t wt[WG_N * LSTR];   // W tile [128][72] bf16
    __shared__ __align__(16) uint16_t xt[BATCH * LSTR];  // x tile [64][72] bf16

    const int t     = threadIdx.x;
    const int wgn   = blockIdx.x & 31;      // OUT_DIM / WG_N = 32 tiles
    const int split = blockIdx.x >> 5;      // 0..27
    const int o0    = wgn * WG_N;
    const int kbase = split * (KBLK * NBLK);

    // pair table: entry i = bf16(c[i&31]) | bf16(c[i>>5])<<16 (low = earlier k)
    #pragma unroll
    for (int e = 0; e < 4; ++e) {
        const int i = t + 256 * e;
        table[i] = f2bf(centroids[i & 31]) | (f2bf(centroids[i >> 5]) << 16);
    }

    const int lane = t & 63;
    const int wave = t >> 6;      // 0..3 -> 32 out-rows each
    const int ln   = lane & 15;
    const int lq   = lane >> 4;   // 0..3

    const int srow = t >> 3;        // W staging: 32 rows per pass
    const int skc  = (t & 7) * 8;   // 8 consecutive k per thread

    const int xrow = t >> 2;        // x staging: 64 rows, 4 threads/row
    const int xseg = (t & 3) * 16;  // 16 bf16 elems per thread

    // per-thread label base pointers (advance by KBLK each blk)
    const int* lbase[4];
    #pragma unroll
    for (int p = 0; p < 4; ++p)
        lbase[p] = labels + (size_t)(o0 + p * 32 + srow) * IN_DIM + kbase + skc;

    f32x4 acc[4][2] = {};   // [batch 16s][out 16s]

    // prologue: labels for blk 0 (nontemporal: 411 MB read-once stream)
    i32x4 pl[4][2];
    #pragma unroll
    for (int p = 0; p < 4; ++p) {
        pl[p][0] = __builtin_nontemporal_load((const i32x4*)lbase[p]);
        pl[p][1] = __builtin_nontemporal_load((const i32x4*)lbase[p] + 1);
    }

    for (int blk = 0; blk < NBLK; ++blk) {
        const int k0 = kbase + blk * KBLK;

        // prefetch blk+1 labels: issued a full iteration ahead of use
        i32x4 npl[4][2];
        if (blk + 1 < NBLK) {
            #pragma unroll
            for (int p = 0; p < 4; ++p) {
                const i32x4* lp = (const i32x4*)(lbase[p] + (blk + 1) * KBLK);
                npl[p][0] = __builtin_nontemporal_load(lp);
                npl[p][1] = __builtin_nontemporal_load(lp + 1);
            }
        }

        __syncthreads();   // wt/xt safe to overwrite (covers table build on blk==0)

        // ---- stage W tile from pl via pair table ----
        #pragma unroll
        for (int p = 0; p < 4; ++p) {
            const int row = p * 32 + srow;
            uint4 w;
            w.x = table[(uint32_t)pl[p][0].x | ((uint32_t)pl[p][0].y << 5)];
            w.y = table[(uint32_t)pl[p][0].z | ((uint32_t)pl[p][0].w << 5)];
            w.z = table[(uint32_t)pl[p][1].x | ((uint32_t)pl[p][1].y << 5)];
            w.w = table[(uint32_t)pl[p][1].z | ((uint32_t)pl[p][1].w << 5)];
            *(uint4*)(wt + row * LSTR + skc) = w;
        }
        // ---- stage x tile: bf16 copy (temporal: xb is L2-resident, reused) ----
        {
            const uint16_t* xp = xb + (size_t)xrow * IN_DIM + k0 + xseg;
            const bf16x8 v0 = *(const bf16x8*)xp;
            const bf16x8 v1 = *(const bf16x8*)(xp + 8);
            *(bf16x8*)(xt + xrow * LSTR + xseg)     = v0;
            *(bf16x8*)(xt + xrow * LSTR + xseg + 8) = v1;
        }
        __syncthreads();

        // ---- consume: 2 k-steps of 32, MFMA 16x16x32 bf16 ----
        #pragma unroll
        for (int ks = 0; ks < 2; ++ks) {
            const int kk = ks * 32 + lq * 8;   // frag: m/n = lane&15, k = (lane>>4)*8+j
            bf16x8 a[4], b[2];
            #pragma unroll
            for (int mt = 0; mt < 4; ++mt)
                a[mt] = *(const bf16x8*)(xt + (mt * 16 + ln) * LSTR + kk);
            #pragma unroll
            for (int nt = 0; nt < 2; ++nt)
                b[nt] = *(const bf16x8*)(wt + (wave * 32 + nt * 16 + ln) * LSTR + kk);
            #pragma unroll
            for (int mt = 0; mt < 4; ++mt)
                #pragma unroll
                for (int nt = 0; nt < 2; ++nt)
                    acc[mt][nt] = __builtin_amdgcn_mfma_f32_16x16x32_bf16(
                        a[mt], b[nt], acc[mt][nt], 0, 0, 0);
        }

        // rotate prefetch registers
        #pragma unroll
        for (int p = 0; p < 4; ++p) {
            pl[p][0] = npl[p][0];
            pl[p][1] = npl[p][1];
        }
    }

    // ---- epilogue: C/D layout col=lane&15 (out), row=(lane>>4)*4+reg (batch).
    // out is only 1 MB and L2/IF-resident: device-scope fp32 atomics are cheap
    // and delete the 58 MB partials round-trip + a third kernel.
    #pragma unroll
    for (int mt = 0; mt < 4; ++mt)
        #pragma unroll
        for (int nt = 0; nt < 2; ++nt) {
            const int o = o0 + wave * 32 + nt * 16 + ln;
            #pragma unroll
            for (int r = 0; r < 4; ++r)
                atomicAdd(out + (size_t)(mt * 16 + lq * 4 + r) * OUT_DIM + o,
                          acc[mt][nt][r]);
        }
}

extern "C" void kernel_launch(void* const* d_in, const int* in_sizes, int n_in,
                              void* d_out, int out_size, void* d_ws, size_t ws_size,
                              hipStream_t stream) {
    const float* x         = (const float*)d_in[0];
    const int*   labels    = (const int*)d_in[1];
    const float* centroids = (const float*)d_in[2];
    const float* bias      = (const float*)d_in[3];
    float* out = (float*)d_out;

    uint32_t* xb = (uint32_t*)d_ws;   // 3.2 MB bf16 x

    prep<<<CONV_BLOCKS + INIT_BLOCKS, 256, 0, stream>>>(x, bias, xb, out);
    qlinear_main<<<32 * SPLITS, 256, 0, stream>>>(labels, centroids,
                                                  (const uint16_t*)xb, out);
}